// Round 3
// baseline (567.039 us; speedup 1.0000x reference)
//
#include <hip/hip_runtime.h>
#include <math.h>

#define NFEAT 128
#define NCLS 40
#define NCLSP 64      // padded class dim (bf16) for pow2 lane math
#define BINROWS 64    // rows per bin
#define NBINMAX 1600  // >= ceil(100000/64)=1563
#define NBLKC 256     // chunks for the binning sort
#define SEGC 7        // ceil(NBINMAX/256)
#define RSMAX 2048    // row_sort LDS stage (bin edges ~Poisson(1024))

typedef short bf16x8 __attribute__((ext_vector_type(8)));
typedef float f32x4 __attribute__((ext_vector_type(4)));

// ---------- bf16 helpers ----------
__device__ __forceinline__ float bf2f(unsigned int lo16) {
  return __uint_as_float((lo16 & 0xffffu) << 16);
}
__device__ __forceinline__ unsigned int f2bf(float x) {  // round-to-nearest-even
  unsigned int u = __float_as_uint(x);
  return (u + 0x7fffu + ((u >> 16) & 1u)) >> 16;
}

// ============================ misc prep: BN fold + weight conversion ============================
// block 0: BN param folding; blocks 1..20: W0/W1 -> bf16, W2 -> 64x128 hi/lo split.
__global__ __launch_bounds__(256) void prep_misc(
    const float* b0, const float* g0, const float* be0,
    const float* rm0, const float* rv0,
    const float* b1, const float* g1, const float* be1,
    const float* rm1, const float* rv1,
    float* sc0, float* sh0, float* sc1, float* sh1,
    const float* __restrict__ W0, const float* __restrict__ W1,
    const float* __restrict__ W2,
    unsigned short* __restrict__ Wb0, unsigned short* __restrict__ Wb1,
    unsigned short* __restrict__ W2hi, unsigned short* __restrict__ W2lo) {
  int t = threadIdx.x;
  if (blockIdx.x == 0) {
    if (t < 128) {
      float s = g0[t] * rsqrtf(rv0[t] + 1e-5f);
      sc0[t] = s;
      sh0[t] = (b0[t] - rm0[t]) * s + be0[t];
    } else {
      int i = t - 128;
      float s = g1[i] * rsqrtf(rv1[i] + 1e-5f);
      sc1[i] = s;
      sh1[i] = (b1[i] - rm1[i]) * s + be1[i];
    }
    return;
  }
  int i = (blockIdx.x - 1) * 256 + t;  // 5120 threads, 8 elems each
  if (i < 4096) {
    const float* W = (i < 2048) ? W0 : W1;
    unsigned short* Wb = (i < 2048) ? Wb0 : Wb1;
    int j = (i < 2048) ? i : i - 2048;
    const float4* p = (const float4*)(W + (size_t)j * 8);
    float4 v0 = p[0], v1 = p[1];
    unsigned int o0 = f2bf(v0.x) | (f2bf(v0.y) << 16);
    unsigned int o1 = f2bf(v0.z) | (f2bf(v0.w) << 16);
    unsigned int o2 = f2bf(v1.x) | (f2bf(v1.y) << 16);
    unsigned int o3 = f2bf(v1.z) | (f2bf(v1.w) << 16);
    ((uint4*)Wb)[j] = make_uint4(o0, o1, o2, o3);
  } else {
    int j = i - 4096;  // chunk of 8 within padded 64x128
    int r = j >> 4;    // padded out-row
    float v[8] = {0.f, 0.f, 0.f, 0.f, 0.f, 0.f, 0.f, 0.f};
    if (r < NCLS) {  // j*8 == r*128 + (j&15)*8 exactly
      const float4* p = (const float4*)(W2 + (size_t)j * 8);
      float4 a = p[0], b = p[1];
      v[0] = a.x; v[1] = a.y; v[2] = a.z; v[3] = a.w;
      v[4] = b.x; v[5] = b.y; v[6] = b.z; v[7] = b.w;
    }
    unsigned int h[8], l[8];
#pragma unroll
    for (int q = 0; q < 8; ++q) {
      h[q] = f2bf(v[q]);
      l[q] = f2bf(v[q] - bf2f(h[q]));
    }
    ((uint4*)W2hi)[j] = make_uint4(h[0] | (h[1] << 16), h[2] | (h[3] << 16),
                                   h[4] | (h[5] << 16), h[6] | (h[7] << 16));
    ((uint4*)W2lo)[j] = make_uint4(l[0] | (l[1] << 16), l[2] | (l[3] << 16),
                                   l[4] | (l[5] << 16), l[6] | (l[7] << 16));
  }
}

// ============================ input conversion (flat row-major) ============================
__global__ void convert_xm(const float* __restrict__ x, const float* __restrict__ Mv,
                           unsigned short* __restrict__ xm, int n) {
  int i = blockIdx.x * 256 + threadIdx.x;  // one 8-elem chunk per thread
  if (i >= n * (NFEAT / 8)) return;
  int row = i >> 4;
  float m = Mv[row];
  const float4* p = (const float4*)(x + (size_t)i * 8);
  float4 v0 = p[0], v1 = p[1];
  unsigned int o0 = f2bf(v0.x * m) | (f2bf(v0.y * m) << 16);
  unsigned int o1 = f2bf(v0.z * m) | (f2bf(v0.w * m) << 16);
  unsigned int o2 = f2bf(v1.x * m) | (f2bf(v1.y * m) << 16);
  unsigned int o3 = f2bf(v1.z * m) | (f2bf(v1.w * m) << 16);
  ((uint4*)xm)[i] = make_uint4(o0, o1, o2, o3);
}

// ============================ stage 1 (merged Z+A): chunk -> 64-row bins ============================
// No LDS staging: the placement pass scatters directly into the chunk's 50KB
// binsC window (L2-absorbed).
__global__ __launch_bounds__(256) void bin_sort2(
    const int* __restrict__ srcZ, const int* __restrict__ dstZ, const float* __restrict__ valZ,
    const int* __restrict__ srcA, const int* __restrict__ dstA, const float* __restrict__ valA,
    int2* __restrict__ DrmZ, int2* __restrict__ DrmA,
    int2* __restrict__ binsCZ, int2* __restrict__ binsCA,
    int E, int nbin, int chunk) {
  __shared__ int cur[NBINMAX];
  __shared__ int ps[256];
  const int t = threadIdx.x;
  int k = blockIdx.x;
  const int* srcp; const int* dstp; const float* valp; int2* Drm; int2* binsC;
  if (k < NBLKC) {
    srcp = srcZ; dstp = dstZ; valp = valZ; Drm = DrmZ; binsC = binsCZ;
  } else {
    k -= NBLKC;
    srcp = srcA; dstp = dstA; valp = valA; Drm = DrmA; binsC = binsCA;
  }
  for (int i = t; i < nbin; i += 256) cur[i] = 0;
  __syncthreads();
  const int e0 = k * chunk, e1 = min(E, e0 + chunk);
#pragma unroll 4
  for (int e = e0 + t; e < e1; e += 256) atomicAdd(&cur[dstp[e] >> 6], 1);
  __syncthreads();
  int loc[SEGC], cnt[SEGC];
  int s = 0;
#pragma unroll
  for (int j = 0; j < SEGC; ++j) {
    int i = t * SEGC + j;
    int v = (i < nbin) ? cur[i] : 0;
    loc[j] = s; cnt[j] = v;
    s += v;
  }
  ps[t] = s;
  __syncthreads();
  for (int o = 1; o < 256; o <<= 1) {
    int x = (t >= o) ? ps[t - o] : 0;
    __syncthreads();
    ps[t] += x;
    __syncthreads();
  }
  int ex = ps[t] - s;
#pragma unroll
  for (int j = 0; j < SEGC; ++j) {
    int i = t * SEGC + j;
    if (i < nbin) {
      int o = ex + loc[j];
      Drm[(size_t)k * nbin + i] = make_int2(e0 + o, cnt[j]);
      cur[i] = o;
    }
  }
  __syncthreads();
#pragma unroll 2
  for (int e = e0 + t; e < e1; e += 256) {
    int d = dstp[e];
    int p = atomicAdd(&cur[d >> 6], 1);
    binsC[e0 + p] = make_int2(srcp[e] | ((d & 63) << 17), __float_as_int(valp[e]));
  }
}

// Transpose run descriptors (row-major by chunk -> bin-major) + per-bin totals. Merged Z+A.
__global__ __launch_bounds__(256) void transposeD2(
    const int2* __restrict__ DrmZ, const int2* __restrict__ DrmA,
    int2* __restrict__ DbmZ, int2* __restrict__ DbmA,
    int* __restrict__ binTotZ, int* __restrict__ binTotA, int nbin, int tdb) {
  __shared__ int2 st[8][256];
  __shared__ int part[256];
  int t = threadIdx.x;
  int b = blockIdx.x;
  const int2* Drm; int2* Dbm; int* binTot;
  if (b < tdb) {
    Drm = DrmZ; Dbm = DbmZ; binTot = binTotZ;
  } else {
    b -= tdb;
    Drm = DrmA; Dbm = DbmA; binTot = binTotA;
  }
  int i0 = b * 8;
#pragma unroll
  for (int j = 0; j < 8; ++j) {
    int i = i0 + j;
    st[j][t] = (i < nbin) ? Drm[(size_t)t * nbin + i] : make_int2(0, 0);
  }
  __syncthreads();
  {
    int j = t >> 5, ks = (t & 31) * 8;
    int i = i0 + j;
    if (i < nbin) {
      int2* q = &Dbm[(size_t)i * NBLKC + ks];
#pragma unroll
      for (int m = 0; m < 8; ++m) q[m] = st[j][ks + m];
    }
    int p = 0;
#pragma unroll
    for (int m = 0; m < 8; ++m) p += st[j][ks + m].y;
    part[t] = p;
  }
  __syncthreads();
  if (t < 8) {
    int s = 0;
    for (int k = 0; k < 32; ++k) s += part[t * 32 + k];
    if (i0 + t < nbin) binTot[i0 + t] = s;
  }
}

// Exclusive scan of binTot -> binStart. Merged: block 0 -> Z, block 1 -> A.
__global__ __launch_bounds__(256) void bin_start2(
    const int* __restrict__ btZ, const int* __restrict__ btA,
    int* __restrict__ bsZ, int* __restrict__ bsA, int nbin) {
  __shared__ int ps[256];
  int t = threadIdx.x;
  const int* bt = (blockIdx.x == 0) ? btZ : btA;
  int* bs = (blockIdx.x == 0) ? bsZ : bsA;
  int C = (nbin + 255) / 256;  // <= 7
  int loc[SEGC + 1];
  int sum = 0;
  for (int j = 0; j < C; ++j) {
    int i = t * C + j;
    loc[j] = sum;
    sum += (i < nbin) ? bt[i] : 0;
  }
  ps[t] = sum;
  __syncthreads();
  for (int o = 1; o < 256; o <<= 1) {
    int x = (t >= o) ? ps[t - o] : 0;
    __syncthreads();
    ps[t] += x;
    __syncthreads();
  }
  int ex = ps[t] - sum;
  for (int j = 0; j < C; ++j) {
    int i = t * C + j;
    if (i < nbin) bs[i] = ex + loc[j];
  }
  if (t == 255) bs[nbin] = ps[255];
}

// ============================ stage 2 (merged Z+A): bin -> full dst-row sort ============================
__global__ __launch_bounds__(256) void row_sort2(
    const int2* __restrict__ DbmZ, const int2* __restrict__ DbmA,
    const int2* __restrict__ binsCZ, const int2* __restrict__ binsCA,
    const int* __restrict__ binStartZ, const int* __restrict__ binStartA,
    int2* __restrict__ bins2Z, int2* __restrict__ bins2A,
    int* __restrict__ rowptrZ, int* __restrict__ rowptrA, int n, int nbin) {
  __shared__ int2 stage[RSMAX];
  __shared__ int ps[256];
  __shared__ int rcnt[BINROWS];
  __shared__ int roff[BINROWS];
  int b = blockIdx.x;
  const int t = threadIdx.x;
  const int2* Dbm; const int2* binsC; const int* binStart; int2* bins2; int* rowptr;
  if (b < nbin) {
    Dbm = DbmZ; binsC = binsCZ; binStart = binStartZ; bins2 = bins2Z; rowptr = rowptrZ;
  } else {
    b -= nbin;
    Dbm = DbmA; binsC = binsCA; binStart = binStartA; bins2 = bins2A; rowptr = rowptrA;
  }
  if (t < BINROWS) rcnt[t] = 0;
  int2 run = Dbm[(size_t)b * NBLKC + t];
  ps[t] = run.y;
  __syncthreads();
  for (int o = 1; o < 256; o <<= 1) {
    int x = (t >= o) ? ps[t - o] : 0;
    __syncthreads();
    ps[t] += x;
    __syncthreads();
  }
  int mystart = ps[t] - run.y;
  for (int j = 0; j < run.y; ++j) {
    int2 en = binsC[run.x + j];
    int idx = mystart + j;
    if (idx < RSMAX) stage[idx] = en;
    atomicAdd(&rcnt[(en.x >> 17) & 63], 1);
  }
  __syncthreads();
  const int bs = binStart[b];
  if (t < BINROWS) {  // wave 0 only: scan 64 row counts
    int c = rcnt[t];
    int s = c;
#pragma unroll
    for (int o = 1; o < 64; o <<= 1) {
      int v = __shfl_up(s, o);
      if (t >= o) s += v;
    }
    int excl = s - c;
    int row = b * BINROWS + t;
    if (row < n) rowptr[row] = bs + excl;
    roff[t] = excl;
  }
  __syncthreads();
  int total = min(ps[255], RSMAX);
  for (int i = t; i < total; i += 256) {
    int2 en = stage[i];
    int row = (en.x >> 17) & 63;
    int p = atomicAdd(&roff[row], 1);
    bins2[bs + p] = en;
  }
  if (b == nbin - 1 && t == 0) rowptr[n] = binStart[nbin];
}

// ============================ SPMM (128 feats), row-sorted, no LDS ============================
// One wave per row; lane owns 4 consecutive feats (8B). Two 32-lane halves each
// gather a DIFFERENT edge per step (one full 256B X-row per edge), 4 steps
// unrolled -> 8 gathers in flight. Halves combined via shfl_xor(32).
// [round-0 form: descriptor block loaded once per 64 edges + shfl broadcast;
//  two rewrites of this loop both regressed -- do not touch.]
template <bool SCALE>
__global__ __launch_bounds__(256) void spmm128_sorted(
    const int* __restrict__ rowptr, const int2* __restrict__ bins2,
    const unsigned short* __restrict__ X, const float* __restrict__ AM,
    unsigned short* __restrict__ Y, int n) {
  int row = (blockIdx.x * 256 + threadIdx.x) >> 6;
  int lane = threadIdx.x & 63;
  if (row >= n) return;
  int s = rowptr[row], d = rowptr[row + 1] - s;
  int half = lane >> 5, l32 = lane & 31;
  float s0 = 0.f, s1 = 0.f, s2 = 0.f, s3 = 0.f;
  for (int kb = 0; kb < d; kb += 64) {
    int rem = min(64, d - kb);
    int2 my = (lane < rem) ? bins2[s + kb + lane] : make_int2(0, 0);  // w==0 pads
    int myc = my.x & 0x1FFFF;
    float myw = __int_as_float(my.y);
    for (int k = 0; k < rem; k += 8) {
#pragma unroll
      for (int st = 0; st < 4; ++st) {
        int idx = k + 2 * st + half;  // <= 63; pad entries have w==0
        int c = __shfl(myc, idx);
        float wv = __shfl(myw, idx);
        uint2 pv = *(const uint2*)(X + (size_t)c * NFEAT + l32 * 4);
        s0 += wv * bf2f(pv.x);
        s1 += wv * bf2f(pv.x >> 16);
        s2 += wv * bf2f(pv.y);
        s3 += wv * bf2f(pv.y >> 16);
      }
    }
  }
  s0 += __shfl_xor(s0, 32); s1 += __shfl_xor(s1, 32);
  s2 += __shfl_xor(s2, 32); s3 += __shfl_xor(s3, 32);
  if (SCALE) {
    float am = AM[row];
    s0 *= am; s1 *= am; s2 *= am; s3 *= am;
  }
  unsigned int pk = half ? (f2bf(s2) | (f2bf(s3) << 16)) : (f2bf(s0) | (f2bf(s1) << 16));
  ((unsigned int*)Y)[(size_t)row * (NFEAT / 2) + l32 * 2 + half] = pk;
}

// ============================ MFMA GEMM 128x128 (+BN+ReLU), flat IO ============================
__global__ __launch_bounds__(256) void gemm_mfma128(
    const unsigned short* __restrict__ Y, const unsigned short* __restrict__ Wb,
    const float* __restrict__ scale, const float* __restrict__ shift,
    unsigned short* __restrict__ Out, int M) {
  const int wave = threadIdx.x >> 6;
  const int lane = threadIdx.x & 63;
  const int quad = lane >> 4;
  const int l16 = lane & 15;
  const int arow = blockIdx.x * 64 + wave * 16 + l16;
  const bool rv = arow < M;

  f32x4 acc[8];
#pragma unroll
  for (int c = 0; c < 8; ++c) acc[c] = (f32x4){0.f, 0.f, 0.f, 0.f};

#pragma unroll
  for (int kc = 0; kc < 128; kc += 32) {
    bf16x8 a = rv ? *(const bf16x8*)(Y + (size_t)arow * 128 + kc + quad * 8)
                  : (bf16x8){0, 0, 0, 0, 0, 0, 0, 0};
#pragma unroll
    for (int c = 0; c < 8; ++c) {
      bf16x8 b = *(const bf16x8*)(Wb + (size_t)(c * 16 + l16) * 128 + kc + quad * 8);
      acc[c] = __builtin_amdgcn_mfma_f32_16x16x32_bf16(a, b, acc[c], 0, 0, 0);
    }
  }

  int orow0 = blockIdx.x * 64 + wave * 16 + quad * 4;
#pragma unroll
  for (int c = 0; c < 8; ++c) {
    int col = c * 16 + l16;
    float sc = scale[col], sh = shift[col];
#pragma unroll
    for (int r = 0; r < 4; ++r) {
      int orow = orow0 + r;
      if (orow < M) {
        float v = fmaxf(acc[c][r] * sc + sh, 0.f);
        Out[(size_t)orow * 128 + col] = (unsigned short)f2bf(v);
      }
    }
  }
}

// ============================ GEMM layer 2 (MFMA, hi/lo split) ============================
// G2[M x 64] bf16 (cols 40..63 zero) = Y[M x 128] @ W2pad[64 x 128]^T where
// W2pad = W2hi + W2lo (bf16 split of fp32 W2) -> fp32-accurate products.
__global__ __launch_bounds__(256) void gemm40_mfma(
    const unsigned short* __restrict__ Y, const unsigned short* __restrict__ Whi,
    const unsigned short* __restrict__ Wlo, unsigned short* __restrict__ G2, int M) {
  const int wave = threadIdx.x >> 6;
  const int lane = threadIdx.x & 63;
  const int quad = lane >> 4;
  const int l16 = lane & 15;
  const int arow = blockIdx.x * 64 + wave * 16 + l16;
  const bool rv = arow < M;

  f32x4 acc[4];
#pragma unroll
  for (int c = 0; c < 4; ++c) acc[c] = (f32x4){0.f, 0.f, 0.f, 0.f};

#pragma unroll
  for (int kc = 0; kc < 128; kc += 32) {
    bf16x8 a = rv ? *(const bf16x8*)(Y + (size_t)arow * 128 + kc + quad * 8)
                  : (bf16x8){0, 0, 0, 0, 0, 0, 0, 0};
#pragma unroll
    for (int c = 0; c < 4; ++c) {
      bf16x8 bh = *(const bf16x8*)(Whi + (size_t)(c * 16 + l16) * 128 + kc + quad * 8);
      bf16x8 bl = *(const bf16x8*)(Wlo + (size_t)(c * 16 + l16) * 128 + kc + quad * 8);
      acc[c] = __builtin_amdgcn_mfma_f32_16x16x32_bf16(a, bh, acc[c], 0, 0, 0);
      acc[c] = __builtin_amdgcn_mfma_f32_16x16x32_bf16(a, bl, acc[c], 0, 0, 0);
    }
  }

  int orow0 = blockIdx.x * 64 + wave * 16 + quad * 4;
#pragma unroll
  for (int c = 0; c < 4; ++c) {
    int col = c * 16 + l16;
#pragma unroll
    for (int r = 0; r < 4; ++r) {
      int orow = orow0 + r;
      if (orow < M) G2[(size_t)orow * NCLSP + col] = (unsigned short)f2bf(acc[c][r]);
    }
  }
}

// ============================ final: spmm(40) + bias + log_softmax ============================
// One wave per row. 4 edges per step: lane = edge*16 + q; q loads 4 bf16 classes
// (8B; 16 lanes x 8B = one 128B G2-row). Reduce over edge bits via shfl_xor(16/32).
__global__ __launch_bounds__(256) void spmm_softmax64(
    const int* __restrict__ rowptr, const int2* __restrict__ bins2,
    const unsigned short* __restrict__ G2, const float* __restrict__ b2,
    float* __restrict__ out, int n) {
  int row = (blockIdx.x * 256 + threadIdx.x) >> 6;
  int lane = threadIdx.x & 63;
  if (row >= n) return;
  const int eidx = lane >> 4, q = lane & 15;
  const bool vq = q < (NCLS / 4);  // 10 quartets cover the 40 real classes
  float4 bv = vq ? *(const float4*)(b2 + q * 4) : make_float4(0.f, 0.f, 0.f, 0.f);

  int s0i = rowptr[row], d = rowptr[row + 1] - s0i;
  float a0 = 0.f, a1 = 0.f, a2 = 0.f, a3 = 0.f;
  for (int kb = 0; kb < d; kb += 64) {
    int rem = min(64, d - kb);
    int2 my = (lane < rem) ? bins2[s0i + kb + lane] : make_int2(0, 0);
    int myc = my.x & 0x1FFFF;
    float myw = __int_as_float(my.y);
    int steps = (rem + 3) >> 2;
#pragma unroll 4
    for (int st = 0; st < steps; ++st) {
      int idx = st * 4 + eidx;  // <= 63; pad entries have w==0
      int c = __shfl(myc, idx);
      float wv = __shfl(myw, idx);
      uint2 pv = *(const uint2*)(G2 + (size_t)c * NCLSP + q * 4);
      a0 += wv * bf2f(pv.x);
      a1 += wv * bf2f(pv.x >> 16);
      a2 += wv * bf2f(pv.y);
      a3 += wv * bf2f(pv.y >> 16);
    }
  }
  a0 += __shfl_xor(a0, 16); a1 += __shfl_xor(a1, 16);
  a2 += __shfl_xor(a2, 16); a3 += __shfl_xor(a3, 16);
  a0 += __shfl_xor(a0, 32); a1 += __shfl_xor(a1, 32);
  a2 += __shfl_xor(a2, 32); a3 += __shfl_xor(a3, 32);
  float z0 = a0 + bv.x, z1 = a1 + bv.y, z2 = a2 + bv.z, z3 = a3 + bv.w;
  bool par = (eidx == 0) && vq;
  float m = par ? fmaxf(fmaxf(z0, z1), fmaxf(z2, z3)) : -INFINITY;
#pragma unroll
  for (int o = 1; o < 64; o <<= 1) m = fmaxf(m, __shfl_xor(m, o));
  float ex = par ? (__expf(z0 - m) + __expf(z1 - m) + __expf(z2 - m) + __expf(z3 - m)) : 0.f;
#pragma unroll
  for (int o = 1; o < 64; o <<= 1) ex += __shfl_xor(ex, o);
  float lg = m + __logf(ex);
  if (par) {
    *(float4*)&out[(size_t)row * NCLS + q * 4] =
        make_float4(z0 - lg, z1 - lg, z2 - lg, z3 - lg);
  }
}

// ============================ launch ============================

extern "C" void kernel_launch(void* const* d_in, const int* in_sizes, int n_in,
                              void* d_out, int out_size, void* d_ws, size_t ws_size,
                              hipStream_t stream) {
  const float* x    = (const float*)d_in[0];
  const float* Mv   = (const float*)d_in[1];
  const float* AM   = (const float*)d_in[2];
  const int* srcZ   = (const int*)d_in[3];
  const int* dstZ   = (const int*)d_in[4];
  const float* valsZ= (const float*)d_in[5];
  const int* src    = (const int*)d_in[6];
  const int* dst    = (const int*)d_in[7];
  const float* vals = (const float*)d_in[8];
  const float* W0   = (const float*)d_in[9];
  const float* b0   = (const float*)d_in[10];
  const float* g0   = (const float*)d_in[11];
  const float* be0  = (const float*)d_in[12];
  const float* rm0  = (const float*)d_in[13];
  const float* rv0  = (const float*)d_in[14];
  const float* W1   = (const float*)d_in[15];
  const float* b1   = (const float*)d_in[16];
  const float* g1   = (const float*)d_in[17];
  const float* be1  = (const float*)d_in[18];
  const float* rm1  = (const float*)d_in[19];
  const float* rv1  = (const float*)d_in[20];
  const float* W2   = (const float*)d_in[21];
  const float* b2   = (const float*)d_in[22];
  float* out = (float*)d_out;

  const int N = in_sizes[1];  // M has shape (N,1)
  const int E = in_sizes[3];
  const int NBIN = (N + BINROWS - 1) / BINROWS;
  const int CHUNK = (E + NBLKC - 1) / NBLKC;  // 6250

  char* w = (char*)d_ws;
  size_t off = 0;
  auto alloc = [&](size_t bytes) -> void* {
    void* p = w + off;
    off = (off + bytes + 255) & ~(size_t)255;
    return p;
  };
  int2* binsCZ = (int2*)alloc((size_t)NBLKC * CHUNK * 8);  // 12.8MB chunk-ordered stage (Z)
  int2* binsCA = (int2*)alloc((size_t)NBLKC * CHUNK * 8);  // 12.8MB chunk-ordered stage (A)
  int* binTotZ = (int*)alloc((size_t)NBIN * 4);
  int* binTotA = (int*)alloc((size_t)NBIN * 4);
  int* binStartZ = (int*)alloc((size_t)(NBIN + 1) * 4);
  int* binStartA = (int*)alloc((size_t)(NBIN + 1) * 4);
  int2* bins2A = (int2*)alloc((size_t)E * 8);              // 12.8MB, lives to the end
  int* rowptrA = (int*)alloc((size_t)(N + 1) * 4);
  unsigned short* xm = (unsigned short*)alloc((size_t)N * NFEAT * 2);    // 25.6MB
  unsigned short* bufA = (unsigned short*)alloc((size_t)N * NFEAT * 2);  // Drm/Dbm -> Y0/Y1 -> G2
  unsigned short* bufB = (unsigned short*)alloc((size_t)N * NFEAT * 2);  // bins2Z -> H0/H1
  float* sc0 = (float*)alloc(128 * 4);
  float* sh0 = (float*)alloc(128 * 4);
  float* sc1 = (float*)alloc(128 * 4);
  float* sh1 = (float*)alloc(128 * 4);
  unsigned short* Wb0 = (unsigned short*)alloc(128 * 128 * 2);
  unsigned short* Wb1 = (unsigned short*)alloc(128 * 128 * 2);
  unsigned short* W2hi = (unsigned short*)alloc(64 * 128 * 2);
  unsigned short* W2lo = (unsigned short*)alloc(64 * 128 * 2);
  // aliases:
  //  - Drm/Dbm (x2, 3.2MB each = 12.8MB) live in bufA until spmmZ writes Y0 there.
  //  - bins2Z + rowptrZ live in bufB until spmmZ consumes them (gemm0 then
  //    overwrites bufB with H0); G2 (N x 64 bf16 = 12.8MB) lives in bufA after Y1 dies.
  const size_t drmBytes = (size_t)NBLKC * NBIN * 8;  // 3,201,024 (mult of 256)
  int2* DrmZ = (int2*)((char*)bufA + 0 * drmBytes);
  int2* DrmA = (int2*)((char*)bufA + 1 * drmBytes);
  int2* DbmZ = (int2*)((char*)bufA + 2 * drmBytes);
  int2* DbmA = (int2*)((char*)bufA + 3 * drmBytes);
  int2* bins2Z = (int2*)bufB;
  int* rowptrZ = (int*)((char*)bufB + 13 * 1024 * 1024);
  unsigned short* G2 = bufA;

  const int RB = (N + 3) / 4;  // 4 rows (waves) per 256-thread block
  const int GB64 = (N + 63) / 64;
  const int TDB = (NBIN + 7) / 8;

  prep_misc<<<21, 256, 0, stream>>>(b0, g0, be0, rm0, rv0, b1, g1, be1, rm1, rv1,
                                    sc0, sh0, sc1, sh1, W0, W1, W2,
                                    Wb0, Wb1, W2hi, W2lo);
  convert_xm<<<(N * (NFEAT / 8) + 255) / 256, 256, 0, stream>>>(x, Mv, xm, N);

  // --- both adjacencies: chunk-bin sort -> full row sort (merged launches) ---
  bin_sort2<<<2 * NBLKC, 256, 0, stream>>>(srcZ, dstZ, valsZ, src, dst, vals,
                                           DrmZ, DrmA, binsCZ, binsCA, E, NBIN, CHUNK);
  transposeD2<<<2 * TDB, 256, 0, stream>>>(DrmZ, DrmA, DbmZ, DbmA, binTotZ, binTotA,
                                           NBIN, TDB);
  bin_start2<<<2, 256, 0, stream>>>(binTotZ, binTotA, binStartZ, binStartA, NBIN);
  row_sort2<<<2 * NBIN, 256, 0, stream>>>(DbmZ, DbmA, binsCZ, binsCA, binStartZ, binStartA,
                                          bins2Z, bins2A, rowptrZ, rowptrA, N, NBIN);

  // layer 0: Y0 = spmm(adjZ, M*x)*AM ; H0 = relu(bn(Y0 @ W0^T + b0))
  spmm128_sorted<true><<<RB, 256, 0, stream>>>(rowptrZ, bins2Z, xm, AM, bufA, N);
  gemm_mfma128<<<GB64, 256, 0, stream>>>(bufA, Wb0, sc0, sh0, bufB, N);

  // layer 1: Y1 = spmm(adj, H0) ; H1 = relu(bn(Y1 @ W1^T + b1))
  spmm128_sorted<false><<<RB, 256, 0, stream>>>(rowptrA, bins2A, bufB,
                                                (const float*)nullptr, bufA, N);
  gemm_mfma128<<<GB64, 256, 0, stream>>>(bufA, Wb1, sc1, sh1, bufB, N);

  // layer 2: G2 = bf16(H1 @ W2^T) padded to 64 cols (GEMM first, segment_sum linear);
  // out = log_softmax(spmm(adj, G2) + b2)
  gemm40_mfma<<<GB64, 256, 0, stream>>>(bufB, W2hi, W2lo, G2, N);
  spmm_softmax64<<<RB, 256, 0, stream>>>(rowptrA, bins2A, G2, b2, out, N);
}

// Round 4
// 529.264 us; speedup vs baseline: 1.0714x; 1.0714x over previous
//
#include <hip/hip_runtime.h>
#include <math.h>

#define NFEAT 128
#define NCLS 40
#define NCLSP 64      // padded class dim (bf16) for pow2 lane math
#define BINROWS 64    // rows per bin
#define NBINMAX 1600  // >= ceil(100000/64)=1563
#define NBLKC 256     // chunks for the binning sort
#define CHUNKMAX 6400 // >= ceil(1600000/256)=6250 ; LDS stage = 50KB
#define SEGC 7        // ceil(NBINMAX/256)
#define RSMAX 2048    // row_sort LDS stage (bin edges ~Poisson(1024))

typedef short bf16x8 __attribute__((ext_vector_type(8)));
typedef float f32x4 __attribute__((ext_vector_type(4)));

// ---------- bf16 helpers ----------
__device__ __forceinline__ float bf2f(unsigned int lo16) {
  return __uint_as_float((lo16 & 0xffffu) << 16);
}
__device__ __forceinline__ unsigned int f2bf(float x) {  // round-to-nearest-even
  unsigned int u = __float_as_uint(x);
  return (u + 0x7fffu + ((u >> 16) & 1u)) >> 16;
}

// ============================ misc prep: BN fold + weight conversion ============================
// block 0: BN param folding; blocks 1..20: W0/W1 -> bf16, W2 -> 64x128 hi/lo split.
__global__ __launch_bounds__(256) void prep_misc(
    const float* b0, const float* g0, const float* be0,
    const float* rm0, const float* rv0,
    const float* b1, const float* g1, const float* be1,
    const float* rm1, const float* rv1,
    float* sc0, float* sh0, float* sc1, float* sh1,
    const float* __restrict__ W0, const float* __restrict__ W1,
    const float* __restrict__ W2,
    unsigned short* __restrict__ Wb0, unsigned short* __restrict__ Wb1,
    unsigned short* __restrict__ W2hi, unsigned short* __restrict__ W2lo) {
  int t = threadIdx.x;
  if (blockIdx.x == 0) {
    if (t < 128) {
      float s = g0[t] * rsqrtf(rv0[t] + 1e-5f);
      sc0[t] = s;
      sh0[t] = (b0[t] - rm0[t]) * s + be0[t];
    } else {
      int i = t - 128;
      float s = g1[i] * rsqrtf(rv1[i] + 1e-5f);
      sc1[i] = s;
      sh1[i] = (b1[i] - rm1[i]) * s + be1[i];
    }
    return;
  }
  int i = (blockIdx.x - 1) * 256 + t;  // 5120 threads, 8 elems each
  if (i < 4096) {
    const float* W = (i < 2048) ? W0 : W1;
    unsigned short* Wb = (i < 2048) ? Wb0 : Wb1;
    int j = (i < 2048) ? i : i - 2048;
    const float4* p = (const float4*)(W + (size_t)j * 8);
    float4 v0 = p[0], v1 = p[1];
    unsigned int o0 = f2bf(v0.x) | (f2bf(v0.y) << 16);
    unsigned int o1 = f2bf(v0.z) | (f2bf(v0.w) << 16);
    unsigned int o2 = f2bf(v1.x) | (f2bf(v1.y) << 16);
    unsigned int o3 = f2bf(v1.z) | (f2bf(v1.w) << 16);
    ((uint4*)Wb)[j] = make_uint4(o0, o1, o2, o3);
  } else {
    int j = i - 4096;  // chunk of 8 within padded 64x128
    int r = j >> 4;    // padded out-row
    float v[8] = {0.f, 0.f, 0.f, 0.f, 0.f, 0.f, 0.f, 0.f};
    if (r < NCLS) {  // j*8 == r*128 + (j&15)*8 exactly
      const float4* p = (const float4*)(W2 + (size_t)j * 8);
      float4 a = p[0], b = p[1];
      v[0] = a.x; v[1] = a.y; v[2] = a.z; v[3] = a.w;
      v[4] = b.x; v[5] = b.y; v[6] = b.z; v[7] = b.w;
    }
    unsigned int h[8], l[8];
#pragma unroll
    for (int q = 0; q < 8; ++q) {
      h[q] = f2bf(v[q]);
      l[q] = f2bf(v[q] - bf2f(h[q]));
    }
    ((uint4*)W2hi)[j] = make_uint4(h[0] | (h[1] << 16), h[2] | (h[3] << 16),
                                   h[4] | (h[5] << 16), h[6] | (h[7] << 16));
    ((uint4*)W2lo)[j] = make_uint4(l[0] | (l[1] << 16), l[2] | (l[3] << 16),
                                   l[4] | (l[5] << 16), l[6] | (l[7] << 16));
  }
}

// ============================ input conversion (flat row-major) ============================
__global__ void convert_xm(const float* __restrict__ x, const float* __restrict__ Mv,
                           unsigned short* __restrict__ xm, int n) {
  int i = blockIdx.x * 256 + threadIdx.x;  // one 8-elem chunk per thread
  if (i >= n * (NFEAT / 8)) return;
  int row = i >> 4;
  float m = Mv[row];
  const float4* p = (const float4*)(x + (size_t)i * 8);
  float4 v0 = p[0], v1 = p[1];
  unsigned int o0 = f2bf(v0.x * m) | (f2bf(v0.y * m) << 16);
  unsigned int o1 = f2bf(v0.z * m) | (f2bf(v0.w * m) << 16);
  unsigned int o2 = f2bf(v1.x * m) | (f2bf(v1.y * m) << 16);
  unsigned int o3 = f2bf(v1.z * m) | (f2bf(v1.w * m) << 16);
  ((uint4*)xm)[i] = make_uint4(o0, o1, o2, o3);
}

// ============================ stage 1 (merged Z+A): chunk -> 64-row bins ============================
// LDS staging is LOAD-BEARING: it converts the random-within-50KB scatter into
// linear full-cacheline global writes. Removing it (round 3) caused ~6x write
// amplification (WRITE_SIZE 26MB -> 144MB) and 2x kernel time. Do not remove.
__global__ __launch_bounds__(256) void bin_sort2(
    const int* __restrict__ srcZ, const int* __restrict__ dstZ, const float* __restrict__ valZ,
    const int* __restrict__ srcA, const int* __restrict__ dstA, const float* __restrict__ valA,
    int2* __restrict__ DrmZ, int2* __restrict__ DrmA,
    int2* __restrict__ binsCZ, int2* __restrict__ binsCA,
    int E, int nbin, int chunk) {
  __shared__ int2 stage[CHUNKMAX];
  __shared__ int cur[NBINMAX];
  __shared__ int ps[256];
  const int t = threadIdx.x;
  int k = blockIdx.x;
  const int* srcp; const int* dstp; const float* valp; int2* Drm; int2* binsC;
  if (k < NBLKC) {
    srcp = srcZ; dstp = dstZ; valp = valZ; Drm = DrmZ; binsC = binsCZ;
  } else {
    k -= NBLKC;
    srcp = srcA; dstp = dstA; valp = valA; Drm = DrmA; binsC = binsCA;
  }
  for (int i = t; i < nbin; i += 256) cur[i] = 0;
  __syncthreads();
  const int e0 = k * chunk, e1 = min(E, e0 + chunk);
#pragma unroll 4
  for (int e = e0 + t; e < e1; e += 256) atomicAdd(&cur[dstp[e] >> 6], 1);
  __syncthreads();
  int loc[SEGC], cnt[SEGC];
  int s = 0;
#pragma unroll
  for (int j = 0; j < SEGC; ++j) {
    int i = t * SEGC + j;
    int v = (i < nbin) ? cur[i] : 0;
    loc[j] = s; cnt[j] = v;
    s += v;
  }
  ps[t] = s;
  __syncthreads();
  for (int o = 1; o < 256; o <<= 1) {
    int x = (t >= o) ? ps[t - o] : 0;
    __syncthreads();
    ps[t] += x;
    __syncthreads();
  }
  int ex = ps[t] - s;
#pragma unroll
  for (int j = 0; j < SEGC; ++j) {
    int i = t * SEGC + j;
    if (i < nbin) {
      int o = ex + loc[j];
      Drm[(size_t)k * nbin + i] = make_int2(e0 + o, cnt[j]);
      cur[i] = o;
    }
  }
  __syncthreads();
#pragma unroll 2
  for (int e = e0 + t; e < e1; e += 256) {
    int d = dstp[e];
    int p = atomicAdd(&cur[d >> 6], 1);
    stage[p] = make_int2(srcp[e] | ((d & 63) << 17), __float_as_int(valp[e]));
  }
  __syncthreads();
  const int n = e1 - e0;
  for (int i = t; i < n; i += 256) binsC[e0 + i] = stage[i];
}

// Transpose run descriptors (row-major by chunk -> bin-major) + per-bin totals. Merged Z+A.
__global__ __launch_bounds__(256) void transposeD2(
    const int2* __restrict__ DrmZ, const int2* __restrict__ DrmA,
    int2* __restrict__ DbmZ, int2* __restrict__ DbmA,
    int* __restrict__ binTotZ, int* __restrict__ binTotA, int nbin, int tdb) {
  __shared__ int2 st[8][256];
  __shared__ int part[256];
  int t = threadIdx.x;
  int b = blockIdx.x;
  const int2* Drm; int2* Dbm; int* binTot;
  if (b < tdb) {
    Drm = DrmZ; Dbm = DbmZ; binTot = binTotZ;
  } else {
    b -= tdb;
    Drm = DrmA; Dbm = DbmA; binTot = binTotA;
  }
  int i0 = b * 8;
#pragma unroll
  for (int j = 0; j < 8; ++j) {
    int i = i0 + j;
    st[j][t] = (i < nbin) ? Drm[(size_t)t * nbin + i] : make_int2(0, 0);
  }
  __syncthreads();
  {
    int j = t >> 5, ks = (t & 31) * 8;
    int i = i0 + j;
    if (i < nbin) {
      int2* q = &Dbm[(size_t)i * NBLKC + ks];
#pragma unroll
      for (int m = 0; m < 8; ++m) q[m] = st[j][ks + m];
    }
    int p = 0;
#pragma unroll
    for (int m = 0; m < 8; ++m) p += st[j][ks + m].y;
    part[t] = p;
  }
  __syncthreads();
  if (t < 8) {
    int s = 0;
    for (int k = 0; k < 32; ++k) s += part[t * 32 + k];
    if (i0 + t < nbin) binTot[i0 + t] = s;
  }
}

// Exclusive scan of binTot -> binStart. Merged: block 0 -> Z, block 1 -> A.
__global__ __launch_bounds__(256) void bin_start2(
    const int* __restrict__ btZ, const int* __restrict__ btA,
    int* __restrict__ bsZ, int* __restrict__ bsA, int nbin) {
  __shared__ int ps[256];
  int t = threadIdx.x;
  const int* bt = (blockIdx.x == 0) ? btZ : btA;
  int* bs = (blockIdx.x == 0) ? bsZ : bsA;
  int C = (nbin + 255) / 256;  // <= 7
  int loc[SEGC + 1];
  int sum = 0;
  for (int j = 0; j < C; ++j) {
    int i = t * C + j;
    loc[j] = sum;
    sum += (i < nbin) ? bt[i] : 0;
  }
  ps[t] = sum;
  __syncthreads();
  for (int o = 1; o < 256; o <<= 1) {
    int x = (t >= o) ? ps[t - o] : 0;
    __syncthreads();
    ps[t] += x;
    __syncthreads();
  }
  int ex = ps[t] - sum;
  for (int j = 0; j < C; ++j) {
    int i = t * C + j;
    if (i < nbin) bs[i] = ex + loc[j];
  }
  if (t == 255) bs[nbin] = ps[255];
}

// ============================ stage 2 (merged Z+A): bin -> full dst-row sort ============================
__global__ __launch_bounds__(256) void row_sort2(
    const int2* __restrict__ DbmZ, const int2* __restrict__ DbmA,
    const int2* __restrict__ binsCZ, const int2* __restrict__ binsCA,
    const int* __restrict__ binStartZ, const int* __restrict__ binStartA,
    int2* __restrict__ bins2Z, int2* __restrict__ bins2A,
    int* __restrict__ rowptrZ, int* __restrict__ rowptrA, int n, int nbin) {
  __shared__ int2 stage[RSMAX];
  __shared__ int ps[256];
  __shared__ int rcnt[BINROWS];
  __shared__ int roff[BINROWS];
  int b = blockIdx.x;
  const int t = threadIdx.x;
  const int2* Dbm; const int2* binsC; const int* binStart; int2* bins2; int* rowptr;
  if (b < nbin) {
    Dbm = DbmZ; binsC = binsCZ; binStart = binStartZ; bins2 = bins2Z; rowptr = rowptrZ;
  } else {
    b -= nbin;
    Dbm = DbmA; binsC = binsCA; binStart = binStartA; bins2 = bins2A; rowptr = rowptrA;
  }
  if (t < BINROWS) rcnt[t] = 0;
  int2 run = Dbm[(size_t)b * NBLKC + t];
  ps[t] = run.y;
  __syncthreads();
  for (int o = 1; o < 256; o <<= 1) {
    int x = (t >= o) ? ps[t - o] : 0;
    __syncthreads();
    ps[t] += x;
    __syncthreads();
  }
  int mystart = ps[t] - run.y;
  for (int j = 0; j < run.y; ++j) {
    int2 en = binsC[run.x + j];
    int idx = mystart + j;
    if (idx < RSMAX) stage[idx] = en;
    atomicAdd(&rcnt[(en.x >> 17) & 63], 1);
  }
  __syncthreads();
  const int bs = binStart[b];
  if (t < BINROWS) {  // wave 0 only: scan 64 row counts
    int c = rcnt[t];
    int s = c;
#pragma unroll
    for (int o = 1; o < 64; o <<= 1) {
      int v = __shfl_up(s, o);
      if (t >= o) s += v;
    }
    int excl = s - c;
    int row = b * BINROWS + t;
    if (row < n) rowptr[row] = bs + excl;
    roff[t] = excl;
  }
  __syncthreads();
  int total = min(ps[255], RSMAX);
  for (int i = t; i < total; i += 256) {
    int2 en = stage[i];
    int row = (en.x >> 17) & 63;
    int p = atomicAdd(&roff[row], 1);
    bins2[bs + p] = en;
  }
  if (b == nbin - 1 && t == 0) rowptr[n] = binStart[nbin];
}

// ============================ SPMM (128 feats), row-sorted, no LDS ============================
// One wave per row; lane owns 4 consecutive feats (8B). Two 32-lane halves each
// gather a DIFFERENT edge per step (one full 256B X-row per edge), 4 steps
// unrolled -> 8 gathers in flight. Halves combined via shfl_xor(32).
// [round-0 form: descriptor block loaded once per 64 edges + shfl broadcast;
//  two rewrites of this loop both regressed -- do not touch.]
template <bool SCALE>
__global__ __launch_bounds__(256) void spmm128_sorted(
    const int* __restrict__ rowptr, const int2* __restrict__ bins2,
    const unsigned short* __restrict__ X, const float* __restrict__ AM,
    unsigned short* __restrict__ Y, int n) {
  int row = (blockIdx.x * 256 + threadIdx.x) >> 6;
  int lane = threadIdx.x & 63;
  if (row >= n) return;
  int s = rowptr[row], d = rowptr[row + 1] - s;
  int half = lane >> 5, l32 = lane & 31;
  float s0 = 0.f, s1 = 0.f, s2 = 0.f, s3 = 0.f;
  for (int kb = 0; kb < d; kb += 64) {
    int rem = min(64, d - kb);
    int2 my = (lane < rem) ? bins2[s + kb + lane] : make_int2(0, 0);  // w==0 pads
    int myc = my.x & 0x1FFFF;
    float myw = __int_as_float(my.y);
    for (int k = 0; k < rem; k += 8) {
#pragma unroll
      for (int st = 0; st < 4; ++st) {
        int idx = k + 2 * st + half;  // <= 63; pad entries have w==0
        int c = __shfl(myc, idx);
        float wv = __shfl(myw, idx);
        uint2 pv = *(const uint2*)(X + (size_t)c * NFEAT + l32 * 4);
        s0 += wv * bf2f(pv.x);
        s1 += wv * bf2f(pv.x >> 16);
        s2 += wv * bf2f(pv.y);
        s3 += wv * bf2f(pv.y >> 16);
      }
    }
  }
  s0 += __shfl_xor(s0, 32); s1 += __shfl_xor(s1, 32);
  s2 += __shfl_xor(s2, 32); s3 += __shfl_xor(s3, 32);
  if (SCALE) {
    float am = AM[row];
    s0 *= am; s1 *= am; s2 *= am; s3 *= am;
  }
  unsigned int pk = half ? (f2bf(s2) | (f2bf(s3) << 16)) : (f2bf(s0) | (f2bf(s1) << 16));
  ((unsigned int*)Y)[(size_t)row * (NFEAT / 2) + l32 * 2 + half] = pk;
}

// ============================ MFMA GEMM 128x128 (+BN+ReLU), flat IO ============================
__global__ __launch_bounds__(256) void gemm_mfma128(
    const unsigned short* __restrict__ Y, const unsigned short* __restrict__ Wb,
    const float* __restrict__ scale, const float* __restrict__ shift,
    unsigned short* __restrict__ Out, int M) {
  const int wave = threadIdx.x >> 6;
  const int lane = threadIdx.x & 63;
  const int quad = lane >> 4;
  const int l16 = lane & 15;
  const int arow = blockIdx.x * 64 + wave * 16 + l16;
  const bool rv = arow < M;

  f32x4 acc[8];
#pragma unroll
  for (int c = 0; c < 8; ++c) acc[c] = (f32x4){0.f, 0.f, 0.f, 0.f};

#pragma unroll
  for (int kc = 0; kc < 128; kc += 32) {
    bf16x8 a = rv ? *(const bf16x8*)(Y + (size_t)arow * 128 + kc + quad * 8)
                  : (bf16x8){0, 0, 0, 0, 0, 0, 0, 0};
#pragma unroll
    for (int c = 0; c < 8; ++c) {
      bf16x8 b = *(const bf16x8*)(Wb + (size_t)(c * 16 + l16) * 128 + kc + quad * 8);
      acc[c] = __builtin_amdgcn_mfma_f32_16x16x32_bf16(a, b, acc[c], 0, 0, 0);
    }
  }

  int orow0 = blockIdx.x * 64 + wave * 16 + quad * 4;
#pragma unroll
  for (int c = 0; c < 8; ++c) {
    int col = c * 16 + l16;
    float sc = scale[col], sh = shift[col];
#pragma unroll
    for (int r = 0; r < 4; ++r) {
      int orow = orow0 + r;
      if (orow < M) {
        float v = fmaxf(acc[c][r] * sc + sh, 0.f);
        Out[(size_t)orow * 128 + col] = (unsigned short)f2bf(v);
      }
    }
  }
}

// ============================ GEMM layer 2 (MFMA, hi/lo split) ============================
// G2[M x 64] bf16 (cols 40..63 zero) = Y[M x 128] @ W2pad[64 x 128]^T where
// W2pad = W2hi + W2lo (bf16 split of fp32 W2) -> fp32-accurate products.
__global__ __launch_bounds__(256) void gemm40_mfma(
    const unsigned short* __restrict__ Y, const unsigned short* __restrict__ Whi,
    const unsigned short* __restrict__ Wlo, unsigned short* __restrict__ G2, int M) {
  const int wave = threadIdx.x >> 6;
  const int lane = threadIdx.x & 63;
  const int quad = lane >> 4;
  const int l16 = lane & 15;
  const int arow = blockIdx.x * 64 + wave * 16 + l16;
  const bool rv = arow < M;

  f32x4 acc[4];
#pragma unroll
  for (int c = 0; c < 4; ++c) acc[c] = (f32x4){0.f, 0.f, 0.f, 0.f};

#pragma unroll
  for (int kc = 0; kc < 128; kc += 32) {
    bf16x8 a = rv ? *(const bf16x8*)(Y + (size_t)arow * 128 + kc + quad * 8)
                  : (bf16x8){0, 0, 0, 0, 0, 0, 0, 0};
#pragma unroll
    for (int c = 0; c < 4; ++c) {
      bf16x8 bh = *(const bf16x8*)(Whi + (size_t)(c * 16 + l16) * 128 + kc + quad * 8);
      bf16x8 bl = *(const bf16x8*)(Wlo + (size_t)(c * 16 + l16) * 128 + kc + quad * 8);
      acc[c] = __builtin_amdgcn_mfma_f32_16x16x32_bf16(a, bh, acc[c], 0, 0, 0);
      acc[c] = __builtin_amdgcn_mfma_f32_16x16x32_bf16(a, bl, acc[c], 0, 0, 0);
    }
  }

  int orow0 = blockIdx.x * 64 + wave * 16 + quad * 4;
#pragma unroll
  for (int c = 0; c < 4; ++c) {
    int col = c * 16 + l16;
#pragma unroll
    for (int r = 0; r < 4; ++r) {
      int orow = orow0 + r;
      if (orow < M) G2[(size_t)orow * NCLSP + col] = (unsigned short)f2bf(acc[c][r]);
    }
  }
}

// ============================ final: spmm(40) + bias + log_softmax ============================
// One wave per row. 4 edges per step: lane = edge*16 + q; q loads 4 bf16 classes
// (8B; 16 lanes x 8B = one 128B G2-row). Reduce over edge bits via shfl_xor(16/32).
__global__ __launch_bounds__(256) void spmm_softmax64(
    const int* __restrict__ rowptr, const int2* __restrict__ bins2,
    const unsigned short* __restrict__ G2, const float* __restrict__ b2,
    float* __restrict__ out, int n) {
  int row = (blockIdx.x * 256 + threadIdx.x) >> 6;
  int lane = threadIdx.x & 63;
  if (row >= n) return;
  const int eidx = lane >> 4, q = lane & 15;
  const bool vq = q < (NCLS / 4);  // 10 quartets cover the 40 real classes
  float4 bv = vq ? *(const float4*)(b2 + q * 4) : make_float4(0.f, 0.f, 0.f, 0.f);

  int s0i = rowptr[row], d = rowptr[row + 1] - s0i;
  float a0 = 0.f, a1 = 0.f, a2 = 0.f, a3 = 0.f;
  for (int kb = 0; kb < d; kb += 64) {
    int rem = min(64, d - kb);
    int2 my = (lane < rem) ? bins2[s0i + kb + lane] : make_int2(0, 0);
    int myc = my.x & 0x1FFFF;
    float myw = __int_as_float(my.y);
    int steps = (rem + 3) >> 2;
#pragma unroll 4
    for (int st = 0; st < steps; ++st) {
      int idx = st * 4 + eidx;  // <= 63; pad entries have w==0
      int c = __shfl(myc, idx);
      float wv = __shfl(myw, idx);
      uint2 pv = *(const uint2*)(G2 + (size_t)c * NCLSP + q * 4);
      a0 += wv * bf2f(pv.x);
      a1 += wv * bf2f(pv.x >> 16);
      a2 += wv * bf2f(pv.y);
      a3 += wv * bf2f(pv.y >> 16);
    }
  }
  a0 += __shfl_xor(a0, 16); a1 += __shfl_xor(a1, 16);
  a2 += __shfl_xor(a2, 16); a3 += __shfl_xor(a3, 16);
  a0 += __shfl_xor(a0, 32); a1 += __shfl_xor(a1, 32);
  a2 += __shfl_xor(a2, 32); a3 += __shfl_xor(a3, 32);
  float z0 = a0 + bv.x, z1 = a1 + bv.y, z2 = a2 + bv.z, z3 = a3 + bv.w;
  bool par = (eidx == 0) && vq;
  float m = par ? fmaxf(fmaxf(z0, z1), fmaxf(z2, z3)) : -INFINITY;
#pragma unroll
  for (int o = 1; o < 64; o <<= 1) m = fmaxf(m, __shfl_xor(m, o));
  float ex = par ? (__expf(z0 - m) + __expf(z1 - m) + __expf(z2 - m) + __expf(z3 - m)) : 0.f;
#pragma unroll
  for (int o = 1; o < 64; o <<= 1) ex += __shfl_xor(ex, o);
  float lg = m + __logf(ex);
  if (par) {
    *(float4*)&out[(size_t)row * NCLS + q * 4] =
        make_float4(z0 - lg, z1 - lg, z2 - lg, z3 - lg);
  }
}

// ============================ launch ============================

extern "C" void kernel_launch(void* const* d_in, const int* in_sizes, int n_in,
                              void* d_out, int out_size, void* d_ws, size_t ws_size,
                              hipStream_t stream) {
  const float* x    = (const float*)d_in[0];
  const float* Mv   = (const float*)d_in[1];
  const float* AM   = (const float*)d_in[2];
  const int* srcZ   = (const int*)d_in[3];
  const int* dstZ   = (const int*)d_in[4];
  const float* valsZ= (const float*)d_in[5];
  const int* src    = (const int*)d_in[6];
  const int* dst    = (const int*)d_in[7];
  const float* vals = (const float*)d_in[8];
  const float* W0   = (const float*)d_in[9];
  const float* b0   = (const float*)d_in[10];
  const float* g0   = (const float*)d_in[11];
  const float* be0  = (const float*)d_in[12];
  const float* rm0  = (const float*)d_in[13];
  const float* rv0  = (const float*)d_in[14];
  const float* W1   = (const float*)d_in[15];
  const float* b1   = (const float*)d_in[16];
  const float* g1   = (const float*)d_in[17];
  const float* be1  = (const float*)d_in[18];
  const float* rm1  = (const float*)d_in[19];
  const float* rv1  = (const float*)d_in[20];
  const float* W2   = (const float*)d_in[21];
  const float* b2   = (const float*)d_in[22];
  float* out = (float*)d_out;

  const int N = in_sizes[1];  // M has shape (N,1)
  const int E = in_sizes[3];
  const int NBIN = (N + BINROWS - 1) / BINROWS;
  const int CHUNK = (E + NBLKC - 1) / NBLKC;  // 6250 <= CHUNKMAX

  char* w = (char*)d_ws;
  size_t off = 0;
  auto alloc = [&](size_t bytes) -> void* {
    void* p = w + off;
    off = (off + bytes + 255) & ~(size_t)255;
    return p;
  };
  int2* binsCZ = (int2*)alloc((size_t)NBLKC * CHUNK * 8);  // 12.8MB chunk-ordered stage (Z)
  int2* binsCA = (int2*)alloc((size_t)NBLKC * CHUNK * 8);  // 12.8MB chunk-ordered stage (A)
  int* binTotZ = (int*)alloc((size_t)NBIN * 4);
  int* binTotA = (int*)alloc((size_t)NBIN * 4);
  int* binStartZ = (int*)alloc((size_t)(NBIN + 1) * 4);
  int* binStartA = (int*)alloc((size_t)(NBIN + 1) * 4);
  int2* bins2A = (int2*)alloc((size_t)E * 8);              // 12.8MB, lives to the end
  int* rowptrA = (int*)alloc((size_t)(N + 1) * 4);
  unsigned short* xm = (unsigned short*)alloc((size_t)N * NFEAT * 2);    // 25.6MB
  unsigned short* bufA = (unsigned short*)alloc((size_t)N * NFEAT * 2);  // Drm/Dbm -> Y0/Y1 -> G2
  unsigned short* bufB = (unsigned short*)alloc((size_t)N * NFEAT * 2);  // bins2Z -> H0/H1
  float* sc0 = (float*)alloc(128 * 4);
  float* sh0 = (float*)alloc(128 * 4);
  float* sc1 = (float*)alloc(128 * 4);
  float* sh1 = (float*)alloc(128 * 4);
  unsigned short* Wb0 = (unsigned short*)alloc(128 * 128 * 2);
  unsigned short* Wb1 = (unsigned short*)alloc(128 * 128 * 2);
  unsigned short* W2hi = (unsigned short*)alloc(64 * 128 * 2);
  unsigned short* W2lo = (unsigned short*)alloc(64 * 128 * 2);
  // aliases:
  //  - Drm/Dbm (x2, 3.2MB each = 12.8MB) live in bufA until spmmZ writes Y0 there.
  //  - bins2Z + rowptrZ live in bufB until spmmZ consumes them (gemm0 then
  //    overwrites bufB with H0); G2 (N x 64 bf16 = 12.8MB) lives in bufA after Y1 dies.
  const size_t drmBytes = (size_t)NBLKC * NBIN * 8;  // 3,201,024 (mult of 256)
  int2* DrmZ = (int2*)((char*)bufA + 0 * drmBytes);
  int2* DrmA = (int2*)((char*)bufA + 1 * drmBytes);
  int2* DbmZ = (int2*)((char*)bufA + 2 * drmBytes);
  int2* DbmA = (int2*)((char*)bufA + 3 * drmBytes);
  int2* bins2Z = (int2*)bufB;
  int* rowptrZ = (int*)((char*)bufB + 13 * 1024 * 1024);
  unsigned short* G2 = bufA;

  const int RB = (N + 3) / 4;  // 4 rows (waves) per 256-thread block
  const int GB64 = (N + 63) / 64;
  const int TDB = (NBIN + 7) / 8;

  prep_misc<<<21, 256, 0, stream>>>(b0, g0, be0, rm0, rv0, b1, g1, be1, rm1, rv1,
                                    sc0, sh0, sc1, sh1, W0, W1, W2,
                                    Wb0, Wb1, W2hi, W2lo);
  convert_xm<<<(N * (NFEAT / 8) + 255) / 256, 256, 0, stream>>>(x, Mv, xm, N);

  // --- both adjacencies: chunk-bin sort -> full row sort (merged launches) ---
  bin_sort2<<<2 * NBLKC, 256, 0, stream>>>(srcZ, dstZ, valsZ, src, dst, vals,
                                           DrmZ, DrmA, binsCZ, binsCA, E, NBIN, CHUNK);
  transposeD2<<<2 * TDB, 256, 0, stream>>>(DrmZ, DrmA, DbmZ, DbmA, binTotZ, binTotA,
                                           NBIN, TDB);
  bin_start2<<<2, 256, 0, stream>>>(binTotZ, binTotA, binStartZ, binStartA, NBIN);
  row_sort2<<<2 * NBIN, 256, 0, stream>>>(DbmZ, DbmA, binsCZ, binsCA, binStartZ, binStartA,
                                          bins2Z, bins2A, rowptrZ, rowptrA, N, NBIN);

  // layer 0: Y0 = spmm(adjZ, M*x)*AM ; H0 = relu(bn(Y0 @ W0^T + b0))
  spmm128_sorted<true><<<RB, 256, 0, stream>>>(rowptrZ, bins2Z, xm, AM, bufA, N);
  gemm_mfma128<<<GB64, 256, 0, stream>>>(bufA, Wb0, sc0, sh0, bufB, N);

  // layer 1: Y1 = spmm(adj, H0) ; H1 = relu(bn(Y1 @ W1^T + b1))
  spmm128_sorted<false><<<RB, 256, 0, stream>>>(rowptrA, bins2A, bufB,
                                                (const float*)nullptr, bufA, N);
  gemm_mfma128<<<GB64, 256, 0, stream>>>(bufA, Wb1, sc1, sh1, bufB, N);

  // layer 2: G2 = bf16(H1 @ W2^T) padded to 64 cols (GEMM first, segment_sum linear);
  // out = log_softmax(spmm(adj, G2) + b2)
  gemm40_mfma<<<GB64, 256, 0, stream>>>(bufB, W2hi, W2lo, G2, N);
  spmm_softmax64<<<RB, 256, 0, stream>>>(rowptrA, bins2A, G2, b2, out, N);
}

// Round 5
// 510.808 us; speedup vs baseline: 1.1101x; 1.0361x over previous
//
#include <hip/hip_runtime.h>
#include <math.h>

#define NFEAT 128
#define NCLS 40
#define NCLSP 64      // padded class dim (bf16) for pow2 lane math
#define BINROWS 64    // rows per bin
#define NBINMAX 1600  // >= ceil(100000/64)=1563
#define NBLKC 256     // chunks for the binning sort
#define CHUNKMAX 6400 // >= ceil(1600000/256)=6250 ; LDS stage = 50KB
#define SEGC 7        // ceil(NBINMAX/256)
#define RSMAX 2048    // per-bin capacity in bins2 (fixed stride) + row_sort LDS stage

typedef short bf16x8 __attribute__((ext_vector_type(8)));
typedef float f32x4 __attribute__((ext_vector_type(4)));

// ---------- bf16 helpers ----------
__device__ __forceinline__ float bf2f(unsigned int lo16) {
  return __uint_as_float((lo16 & 0xffffu) << 16);
}
__device__ __forceinline__ unsigned int f2bf(float x) {  // round-to-nearest-even
  unsigned int u = __float_as_uint(x);
  return (u + 0x7fffu + ((u >> 16) & 1u)) >> 16;
}

// ============================ merged prep: BN fold + W conv + x*M conv ============================
// block 0: BN fold; blocks 1..20: W0/W1 bf16 + W2 hi/lo split; blocks 21..: x*M -> bf16.
__global__ __launch_bounds__(256) void prep_all(
    const float* b0, const float* g0, const float* be0,
    const float* rm0, const float* rv0,
    const float* b1, const float* g1, const float* be1,
    const float* rm1, const float* rv1,
    float* sc0, float* sh0, float* sc1, float* sh1,
    const float* __restrict__ W0, const float* __restrict__ W1,
    const float* __restrict__ W2,
    unsigned short* __restrict__ Wb0, unsigned short* __restrict__ Wb1,
    unsigned short* __restrict__ W2hi, unsigned short* __restrict__ W2lo,
    const float* __restrict__ x, const float* __restrict__ Mv,
    unsigned short* __restrict__ xm, int n) {
  int t = threadIdx.x;
  if (blockIdx.x == 0) {
    if (t < 128) {
      float s = g0[t] * rsqrtf(rv0[t] + 1e-5f);
      sc0[t] = s;
      sh0[t] = (b0[t] - rm0[t]) * s + be0[t];
    } else {
      int i = t - 128;
      float s = g1[i] * rsqrtf(rv1[i] + 1e-5f);
      sc1[i] = s;
      sh1[i] = (b1[i] - rm1[i]) * s + be1[i];
    }
    return;
  }
  if (blockIdx.x <= 20) {
    int i = (blockIdx.x - 1) * 256 + t;  // 5120 threads, 8 elems each
    if (i < 4096) {
      const float* W = (i < 2048) ? W0 : W1;
      unsigned short* Wb = (i < 2048) ? Wb0 : Wb1;
      int j = (i < 2048) ? i : i - 2048;
      const float4* p = (const float4*)(W + (size_t)j * 8);
      float4 v0 = p[0], v1 = p[1];
      unsigned int o0 = f2bf(v0.x) | (f2bf(v0.y) << 16);
      unsigned int o1 = f2bf(v0.z) | (f2bf(v0.w) << 16);
      unsigned int o2 = f2bf(v1.x) | (f2bf(v1.y) << 16);
      unsigned int o3 = f2bf(v1.z) | (f2bf(v1.w) << 16);
      ((uint4*)Wb)[j] = make_uint4(o0, o1, o2, o3);
    } else {
      int j = i - 4096;  // chunk of 8 within padded 64x128
      int r = j >> 4;    // padded out-row
      float v[8] = {0.f, 0.f, 0.f, 0.f, 0.f, 0.f, 0.f, 0.f};
      if (r < NCLS) {  // j*8 == r*128 + (j&15)*8 exactly
        const float4* p = (const float4*)(W2 + (size_t)j * 8);
        float4 a = p[0], b = p[1];
        v[0] = a.x; v[1] = a.y; v[2] = a.z; v[3] = a.w;
        v[4] = b.x; v[5] = b.y; v[6] = b.z; v[7] = b.w;
      }
      unsigned int h[8], l[8];
#pragma unroll
      for (int q = 0; q < 8; ++q) {
        h[q] = f2bf(v[q]);
        l[q] = f2bf(v[q] - bf2f(h[q]));
      }
      ((uint4*)W2hi)[j] = make_uint4(h[0] | (h[1] << 16), h[2] | (h[3] << 16),
                                     h[4] | (h[5] << 16), h[6] | (h[7] << 16));
      ((uint4*)W2lo)[j] = make_uint4(l[0] | (l[1] << 16), l[2] | (l[3] << 16),
                                     l[4] | (l[5] << 16), l[6] | (l[7] << 16));
    }
    return;
  }
  int i = (blockIdx.x - 21) * 256 + t;  // one 8-elem chunk per thread
  if (i >= n * (NFEAT / 8)) return;
  int row = i >> 4;
  float m = Mv[row];
  const float4* p = (const float4*)(x + (size_t)i * 8);
  float4 v0 = p[0], v1 = p[1];
  unsigned int o0 = f2bf(v0.x * m) | (f2bf(v0.y * m) << 16);
  unsigned int o1 = f2bf(v0.z * m) | (f2bf(v0.w * m) << 16);
  unsigned int o2 = f2bf(v1.x * m) | (f2bf(v1.y * m) << 16);
  unsigned int o3 = f2bf(v1.z * m) | (f2bf(v1.w * m) << 16);
  ((uint4*)xm)[i] = make_uint4(o0, o1, o2, o3);
}

// ============================ stage 1 (merged Z+A): chunk -> 64-row bins ============================
// LDS staging is LOAD-BEARING: it converts the random-within-50KB scatter into
// linear full-cacheline global writes. Removing it (round 3) caused ~6x write
// amplification (WRITE_SIZE 26MB -> 144MB) and 2x kernel time. Do not remove.
__global__ __launch_bounds__(256) void bin_sort2(
    const int* __restrict__ srcZ, const int* __restrict__ dstZ, const float* __restrict__ valZ,
    const int* __restrict__ srcA, const int* __restrict__ dstA, const float* __restrict__ valA,
    int2* __restrict__ DrmZ, int2* __restrict__ DrmA,
    int2* __restrict__ binsCZ, int2* __restrict__ binsCA,
    int E, int nbin, int chunk) {
  __shared__ int2 stage[CHUNKMAX];
  __shared__ int cur[NBINMAX];
  __shared__ int ps[256];
  const int t = threadIdx.x;
  int k = blockIdx.x;
  const int* srcp; const int* dstp; const float* valp; int2* Drm; int2* binsC;
  if (k < NBLKC) {
    srcp = srcZ; dstp = dstZ; valp = valZ; Drm = DrmZ; binsC = binsCZ;
  } else {
    k -= NBLKC;
    srcp = srcA; dstp = dstA; valp = valA; Drm = DrmA; binsC = binsCA;
  }
  for (int i = t; i < nbin; i += 256) cur[i] = 0;
  __syncthreads();
  const int e0 = k * chunk, e1 = min(E, e0 + chunk);
#pragma unroll 4
  for (int e = e0 + t; e < e1; e += 256) atomicAdd(&cur[dstp[e] >> 6], 1);
  __syncthreads();
  int loc[SEGC], cnt[SEGC];
  int s = 0;
#pragma unroll
  for (int j = 0; j < SEGC; ++j) {
    int i = t * SEGC + j;
    int v = (i < nbin) ? cur[i] : 0;
    loc[j] = s; cnt[j] = v;
    s += v;
  }
  ps[t] = s;
  __syncthreads();
  for (int o = 1; o < 256; o <<= 1) {
    int x = (t >= o) ? ps[t - o] : 0;
    __syncthreads();
    ps[t] += x;
    __syncthreads();
  }
  int ex = ps[t] - s;
#pragma unroll
  for (int j = 0; j < SEGC; ++j) {
    int i = t * SEGC + j;
    if (i < nbin) {
      int o = ex + loc[j];
      Drm[(size_t)k * nbin + i] = make_int2(e0 + o, cnt[j]);
      cur[i] = o;
    }
  }
  __syncthreads();
#pragma unroll 2
  for (int e = e0 + t; e < e1; e += 256) {
    int d = dstp[e];
    int p = atomicAdd(&cur[d >> 6], 1);
    stage[p] = make_int2(srcp[e] | ((d & 63) << 17), __float_as_int(valp[e]));
  }
  __syncthreads();
  const int n = e1 - e0;
  for (int i = t; i < n; i += 256) binsC[e0 + i] = stage[i];
}

// Transpose run descriptors (row-major by chunk -> bin-major). Merged Z+A.
// (binTot/binStart machinery removed: bins2 now has fixed per-bin stride RSMAX.)
__global__ __launch_bounds__(256) void transposeD2(
    const int2* __restrict__ DrmZ, const int2* __restrict__ DrmA,
    int2* __restrict__ DbmZ, int2* __restrict__ DbmA, int nbin, int tdb) {
  __shared__ int2 st[8][256];
  int t = threadIdx.x;
  int b = blockIdx.x;
  const int2* Drm; int2* Dbm;
  if (b < tdb) {
    Drm = DrmZ; Dbm = DbmZ;
  } else {
    b -= tdb;
    Drm = DrmA; Dbm = DbmA;
  }
  int i0 = b * 8;
#pragma unroll
  for (int j = 0; j < 8; ++j) {
    int i = i0 + j;
    st[j][t] = (i < nbin) ? Drm[(size_t)t * nbin + i] : make_int2(0, 0);
  }
  __syncthreads();
  {
    int j = t >> 5, ks = (t & 31) * 8;
    int i = i0 + j;
    if (i < nbin) {
      int2* q = &Dbm[(size_t)i * NBLKC + ks];
#pragma unroll
      for (int m = 0; m < 8; ++m) q[m] = st[j][ks + m];
    }
  }
}

// ============================ stage 2 (merged Z+A): bin -> full dst-row sort ============================
// bins2 layout: bin b occupies [b*RSMAX, b*RSMAX+cnt). rowdesc[row] = (start, deg)
// -- absolute offsets, so no global compaction (binStart scan kernel) needed.
__global__ __launch_bounds__(256) void row_sort2(
    const int2* __restrict__ DbmZ, const int2* __restrict__ DbmA,
    const int2* __restrict__ binsCZ, const int2* __restrict__ binsCA,
    int2* __restrict__ bins2Z, int2* __restrict__ bins2A,
    int2* __restrict__ rdZ, int2* __restrict__ rdA, int n, int nbin) {
  __shared__ int2 stage[RSMAX];
  __shared__ int ps[256];
  __shared__ int rcnt[BINROWS];
  __shared__ int roff[BINROWS];
  int b = blockIdx.x;
  const int t = threadIdx.x;
  const int2* Dbm; const int2* binsC; int2* bins2; int2* rowdesc;
  if (b < nbin) {
    Dbm = DbmZ; binsC = binsCZ; bins2 = bins2Z; rowdesc = rdZ;
  } else {
    b -= nbin;
    Dbm = DbmA; binsC = binsCA; bins2 = bins2A; rowdesc = rdA;
  }
  if (t < BINROWS) rcnt[t] = 0;
  int2 run = Dbm[(size_t)b * NBLKC + t];
  ps[t] = run.y;
  __syncthreads();
  for (int o = 1; o < 256; o <<= 1) {
    int x = (t >= o) ? ps[t - o] : 0;
    __syncthreads();
    ps[t] += x;
    __syncthreads();
  }
  int mystart = ps[t] - run.y;
  for (int j = 0; j < run.y; ++j) {
    int2 en = binsC[run.x + j];
    int idx = mystart + j;
    if (idx < RSMAX) stage[idx] = en;
    atomicAdd(&rcnt[(en.x >> 17) & 63], 1);
  }
  __syncthreads();
  const int bs = b * RSMAX;
  if (t < BINROWS) {  // wave 0 only: scan 64 row counts
    int c = rcnt[t];
    int s = c;
#pragma unroll
    for (int o = 1; o < 64; o <<= 1) {
      int v = __shfl_up(s, o);
      if (t >= o) s += v;
    }
    int excl = s - c;
    int row = b * BINROWS + t;
    if (row < n) rowdesc[row] = make_int2(bs + excl, c);
    roff[t] = excl;
  }
  __syncthreads();
  int total = min(ps[255], RSMAX);
  for (int i = t; i < total; i += 256) {
    int2 en = stage[i];
    int row = (en.x >> 17) & 63;
    int p = atomicAdd(&roff[row], 1);
    bins2[bs + p] = en;
  }
}

// ============================ SPMM (128 feats), row-sorted, no LDS ============================
// One wave per row; lane owns 4 consecutive feats (8B). Two 32-lane halves each
// gather a DIFFERENT edge per step (one full 256B X-row per edge), 4 steps
// unrolled -> 8 gathers in flight. Halves combined via shfl_xor(32).
// [round-0 form: descriptor block loaded once per 64 edges + shfl broadcast;
//  two rewrites of this loop both regressed -- do not touch the body.]
template <bool SCALE>
__global__ __launch_bounds__(256) void spmm128_sorted(
    const int2* __restrict__ rowdesc, const int2* __restrict__ bins2,
    const unsigned short* __restrict__ X, const float* __restrict__ AM,
    unsigned short* __restrict__ Y, int n) {
  int row = (blockIdx.x * 256 + threadIdx.x) >> 6;
  int lane = threadIdx.x & 63;
  if (row >= n) return;
  int2 rd = rowdesc[row];
  int s = rd.x, d = rd.y;
  int half = lane >> 5, l32 = lane & 31;
  float s0 = 0.f, s1 = 0.f, s2 = 0.f, s3 = 0.f;
  for (int kb = 0; kb < d; kb += 64) {
    int rem = min(64, d - kb);
    int2 my = (lane < rem) ? bins2[s + kb + lane] : make_int2(0, 0);  // w==0 pads
    int myc = my.x & 0x1FFFF;
    float myw = __int_as_float(my.y);
    for (int k = 0; k < rem; k += 8) {
#pragma unroll
      for (int st = 0; st < 4; ++st) {
        int idx = k + 2 * st + half;  // <= 63; pad entries have w==0
        int c = __shfl(myc, idx);
        float wv = __shfl(myw, idx);
        uint2 pv = *(const uint2*)(X + (size_t)c * NFEAT + l32 * 4);
        s0 += wv * bf2f(pv.x);
        s1 += wv * bf2f(pv.x >> 16);
        s2 += wv * bf2f(pv.y);
        s3 += wv * bf2f(pv.y >> 16);
      }
    }
  }
  s0 += __shfl_xor(s0, 32); s1 += __shfl_xor(s1, 32);
  s2 += __shfl_xor(s2, 32); s3 += __shfl_xor(s3, 32);
  if (SCALE) {
    float am = AM[row];
    s0 *= am; s1 *= am; s2 *= am; s3 *= am;
  }
  unsigned int pk = half ? (f2bf(s2) | (f2bf(s3) << 16)) : (f2bf(s0) | (f2bf(s1) << 16));
  ((unsigned int*)Y)[(size_t)row * (NFEAT / 2) + l32 * 2 + half] = pk;
}

// ============================ MFMA GEMM 128x128 (+BN+ReLU), flat IO ============================
// FUSE_G2=false (layer 0): Out = relu(bn(Y@W^T)) as bf16.
// FUSE_G2=true  (layer 1): H1 = relu(bn(Y@W1^T)) stays on-chip (LDS transpose
// staging), then G2 = H1 @ W2pad^T (hi+lo bf16 split of fp32 W2) is written.
// Saves writing+re-reading the 25.6MB H1 buffer and one kernel launch; the
// bf16 rounding point of H1 is identical to the unfused path.
template <bool FUSE_G2>
__global__ __launch_bounds__(256) void gemm_mfma128(
    const unsigned short* __restrict__ Y, const unsigned short* __restrict__ Wb,
    const float* __restrict__ scale, const float* __restrict__ shift,
    unsigned short* __restrict__ Out,
    const unsigned short* __restrict__ Whi, const unsigned short* __restrict__ Wlo,
    unsigned short* __restrict__ G2, int M) {
  const int wave = threadIdx.x >> 6;
  const int lane = threadIdx.x & 63;
  const int quad = lane >> 4;
  const int l16 = lane & 15;
  const int arow = blockIdx.x * 64 + wave * 16 + l16;
  const bool rv = arow < M;

  f32x4 acc[8];
#pragma unroll
  for (int c = 0; c < 8; ++c) acc[c] = (f32x4){0.f, 0.f, 0.f, 0.f};

#pragma unroll
  for (int kc = 0; kc < 128; kc += 32) {
    bf16x8 a = rv ? *(const bf16x8*)(Y + (size_t)arow * 128 + kc + quad * 8)
                  : (bf16x8){0, 0, 0, 0, 0, 0, 0, 0};
#pragma unroll
    for (int c = 0; c < 8; ++c) {
      bf16x8 b = *(const bf16x8*)(Wb + (size_t)(c * 16 + l16) * 128 + kc + quad * 8);
      acc[c] = __builtin_amdgcn_mfma_f32_16x16x32_bf16(a, b, acc[c], 0, 0, 0);
    }
  }

  const int orow0 = blockIdx.x * 64 + wave * 16 + quad * 4;

  if constexpr (!FUSE_G2) {
#pragma unroll
    for (int c = 0; c < 8; ++c) {
      int col = c * 16 + l16;
      float sc = scale[col], sh = shift[col];
#pragma unroll
      for (int r = 0; r < 4; ++r) {
        int orow = orow0 + r;
        if (orow < M) {
          float v = fmaxf(acc[c][r] * sc + sh, 0.f);
          Out[(size_t)orow * 128 + col] = (unsigned short)f2bf(v);
        }
      }
    }
  } else {
    // stage H1 tile (64x128 bf16) in LDS; each wave only touches its own 16 rows
    // (rows partitioned by wave for both write and read), +8-short row pad for banks.
    __shared__ unsigned short Ht[64][136];
    const int lrow0 = wave * 16 + quad * 4;
#pragma unroll
    for (int c = 0; c < 8; ++c) {
      int col = c * 16 + l16;
      float sc = scale[col], sh = shift[col];
#pragma unroll
      for (int r = 0; r < 4; ++r) {
        float v = fmaxf(acc[c][r] * sc + sh, 0.f);
        Ht[lrow0 + r][col] = (unsigned short)f2bf(v);
      }
    }
    __syncthreads();
    bf16x8 af[4];
#pragma unroll
    for (int kc = 0; kc < 4; ++kc)
      af[kc] = *(const bf16x8*)(&Ht[wave * 16 + l16][kc * 32 + quad * 8]);
    f32x4 acc2[4];
#pragma unroll
    for (int c2 = 0; c2 < 4; ++c2) acc2[c2] = (f32x4){0.f, 0.f, 0.f, 0.f};
#pragma unroll
    for (int kc = 0; kc < 4; ++kc) {
#pragma unroll
      for (int c2 = 0; c2 < 4; ++c2) {
        bf16x8 bh = *(const bf16x8*)(Whi + (size_t)(c2 * 16 + l16) * 128 + kc * 32 + quad * 8);
        bf16x8 bl = *(const bf16x8*)(Wlo + (size_t)(c2 * 16 + l16) * 128 + kc * 32 + quad * 8);
        acc2[c2] = __builtin_amdgcn_mfma_f32_16x16x32_bf16(af[kc], bh, acc2[c2], 0, 0, 0);
        acc2[c2] = __builtin_amdgcn_mfma_f32_16x16x32_bf16(af[kc], bl, acc2[c2], 0, 0, 0);
      }
    }
#pragma unroll
    for (int c2 = 0; c2 < 4; ++c2) {
      int col = c2 * 16 + l16;
#pragma unroll
      for (int r = 0; r < 4; ++r) {
        int orow = orow0 + r;
        if (orow < M) G2[(size_t)orow * NCLSP + col] = (unsigned short)f2bf(acc2[c2][r]);
      }
    }
  }
}

// ============================ final: spmm(40) + bias + log_softmax ============================
// One wave per row. 4 edges per step: lane = edge*16 + q; q loads 4 bf16 classes
// (8B; 16 lanes x 8B = one 128B G2-row). Reduce over edge bits via shfl_xor(16/32).
__global__ __launch_bounds__(256) void spmm_softmax64(
    const int2* __restrict__ rowdesc, const int2* __restrict__ bins2,
    const unsigned short* __restrict__ G2, const float* __restrict__ b2,
    float* __restrict__ out, int n) {
  int row = (blockIdx.x * 256 + threadIdx.x) >> 6;
  int lane = threadIdx.x & 63;
  if (row >= n) return;
  const int eidx = lane >> 4, q = lane & 15;
  const bool vq = q < (NCLS / 4);  // 10 quartets cover the 40 real classes
  float4 bv = vq ? *(const float4*)(b2 + q * 4) : make_float4(0.f, 0.f, 0.f, 0.f);

  int2 rdv = rowdesc[row];
  int s0i = rdv.x, d = rdv.y;
  float a0 = 0.f, a1 = 0.f, a2 = 0.f, a3 = 0.f;
  for (int kb = 0; kb < d; kb += 64) {
    int rem = min(64, d - kb);
    int2 my = (lane < rem) ? bins2[s0i + kb + lane] : make_int2(0, 0);
    int myc = my.x & 0x1FFFF;
    float myw = __int_as_float(my.y);
    int steps = (rem + 3) >> 2;
#pragma unroll 4
    for (int st = 0; st < steps; ++st) {
      int idx = st * 4 + eidx;  // <= 63; pad entries have w==0
      int c = __shfl(myc, idx);
      float wv = __shfl(myw, idx);
      uint2 pv = *(const uint2*)(G2 + (size_t)c * NCLSP + q * 4);
      a0 += wv * bf2f(pv.x);
      a1 += wv * bf2f(pv.x >> 16);
      a2 += wv * bf2f(pv.y);
      a3 += wv * bf2f(pv.y >> 16);
    }
  }
  a0 += __shfl_xor(a0, 16); a1 += __shfl_xor(a1, 16);
  a2 += __shfl_xor(a2, 16); a3 += __shfl_xor(a3, 16);
  a0 += __shfl_xor(a0, 32); a1 += __shfl_xor(a1, 32);
  a2 += __shfl_xor(a2, 32); a3 += __shfl_xor(a3, 32);
  float z0 = a0 + bv.x, z1 = a1 + bv.y, z2 = a2 + bv.z, z3 = a3 + bv.w;
  bool par = (eidx == 0) && vq;
  float m = par ? fmaxf(fmaxf(z0, z1), fmaxf(z2, z3)) : -INFINITY;
#pragma unroll
  for (int o = 1; o < 64; o <<= 1) m = fmaxf(m, __shfl_xor(m, o));
  float ex = par ? (__expf(z0 - m) + __expf(z1 - m) + __expf(z2 - m) + __expf(z3 - m)) : 0.f;
#pragma unroll
  for (int o = 1; o < 64; o <<= 1) ex += __shfl_xor(ex, o);
  float lg = m + __logf(ex);
  if (par) {
    *(float4*)&out[(size_t)row * NCLS + q * 4] =
        make_float4(z0 - lg, z1 - lg, z2 - lg, z3 - lg);
  }
}

// ============================ launch ============================

extern "C" void kernel_launch(void* const* d_in, const int* in_sizes, int n_in,
                              void* d_out, int out_size, void* d_ws, size_t ws_size,
                              hipStream_t stream) {
  const float* x    = (const float*)d_in[0];
  const float* Mv   = (const float*)d_in[1];
  const float* AM   = (const float*)d_in[2];
  const int* srcZ   = (const int*)d_in[3];
  const int* dstZ   = (const int*)d_in[4];
  const float* valsZ= (const float*)d_in[5];
  const int* src    = (const int*)d_in[6];
  const int* dst    = (const int*)d_in[7];
  const float* vals = (const float*)d_in[8];
  const float* W0   = (const float*)d_in[9];
  const float* b0   = (const float*)d_in[10];
  const float* g0   = (const float*)d_in[11];
  const float* be0  = (const float*)d_in[12];
  const float* rm0  = (const float*)d_in[13];
  const float* rv0  = (const float*)d_in[14];
  const float* W1   = (const float*)d_in[15];
  const float* b1   = (const float*)d_in[16];
  const float* g1   = (const float*)d_in[17];
  const float* be1  = (const float*)d_in[18];
  const float* rm1  = (const float*)d_in[19];
  const float* rv1  = (const float*)d_in[20];
  const float* W2   = (const float*)d_in[21];
  const float* b2   = (const float*)d_in[22];
  float* out = (float*)d_out;

  const int N = in_sizes[1];  // M has shape (N,1)
  const int E = in_sizes[3];
  const int NBIN = (N + BINROWS - 1) / BINROWS;
  const int CHUNK = (E + NBLKC - 1) / NBLKC;  // 6250 <= CHUNKMAX

  char* w = (char*)d_ws;
  size_t off = 0;
  auto alloc = [&](size_t bytes) -> void* {
    void* p = w + off;
    off = (off + bytes + 255) & ~(size_t)255;
    return p;
  };
  const size_t bins2Bytes = (size_t)NBIN * RSMAX * 8;     // 25.6MB fixed-stride layout
  const size_t bufBytes = (size_t)N * NFEAT * 2;          // 25.6MB
  int2* binsCZ = (int2*)alloc((size_t)NBLKC * CHUNK * 8); // 12.8MB chunk-ordered stage (Z)
  int2* binsCA = (int2*)alloc((size_t)NBLKC * CHUNK * 8); // 12.8MB chunk-ordered stage (A)
  int2* bins2A = (int2*)alloc(bins2Bytes);                // lives to the end
  int2* rdZ = (int2*)alloc((size_t)N * 8);                // rowdesc (start,deg) Z
  int2* rdA = (int2*)alloc((size_t)N * 8);                // rowdesc (start,deg) A
  unsigned short* xm = (unsigned short*)alloc(bufBytes);  // 25.6MB
  unsigned short* bufA = (unsigned short*)alloc(bufBytes);                 // Drm/Dbm -> Y0 -> Y1
  unsigned short* bufB = (unsigned short*)alloc(bins2Bytes > bufBytes ? bins2Bytes : bufBytes);
  float* sc0 = (float*)alloc(128 * 4);
  float* sh0 = (float*)alloc(128 * 4);
  float* sc1 = (float*)alloc(128 * 4);
  float* sh1 = (float*)alloc(128 * 4);
  unsigned short* Wb0 = (unsigned short*)alloc(128 * 128 * 2);
  unsigned short* Wb1 = (unsigned short*)alloc(128 * 128 * 2);
  unsigned short* W2hi = (unsigned short*)alloc(64 * 128 * 2);
  unsigned short* W2lo = (unsigned short*)alloc(64 * 128 * 2);
  // aliases:
  //  - Drm/Dbm (x2, 3.2MB each = 12.8MB) live in bufA until spmmZ writes Y0 there.
  //  - bins2Z (25.6MB fixed-stride) lives in bufB until spmmZ consumes it
  //    (gemm0 then overwrites bufB with H0); G2 (N x 64 bf16 = 12.8MB) lives in
  //    bufB after H0 dies (fused gemm1 reads Y1 from bufA, writes G2 to bufB).
  const size_t drmBytes = (size_t)NBLKC * NBIN * 8;  // 3,201,024 (mult of 256)
  int2* DrmZ = (int2*)((char*)bufA + 0 * drmBytes);
  int2* DrmA = (int2*)((char*)bufA + 1 * drmBytes);
  int2* DbmZ = (int2*)((char*)bufA + 2 * drmBytes);
  int2* DbmA = (int2*)((char*)bufA + 3 * drmBytes);
  int2* bins2Z = (int2*)bufB;
  unsigned short* G2 = bufB;

  const int RB = (N + 3) / 4;  // 4 rows (waves) per 256-thread block
  const int GB64 = (N + 63) / 64;
  const int TDB = (NBIN + 7) / 8;
  const int CONVB = (N * (NFEAT / 8) + 255) / 256;

  prep_all<<<21 + CONVB, 256, 0, stream>>>(b0, g0, be0, rm0, rv0, b1, g1, be1, rm1, rv1,
                                           sc0, sh0, sc1, sh1, W0, W1, W2,
                                           Wb0, Wb1, W2hi, W2lo, x, Mv, xm, N);

  // --- both adjacencies: chunk-bin sort -> full row sort (merged launches) ---
  bin_sort2<<<2 * NBLKC, 256, 0, stream>>>(srcZ, dstZ, valsZ, src, dst, vals,
                                           DrmZ, DrmA, binsCZ, binsCA, E, NBIN, CHUNK);
  transposeD2<<<2 * TDB, 256, 0, stream>>>(DrmZ, DrmA, DbmZ, DbmA, NBIN, TDB);
  row_sort2<<<2 * NBIN, 256, 0, stream>>>(DbmZ, DbmA, binsCZ, binsCA,
                                          bins2Z, bins2A, rdZ, rdA, N, NBIN);

  // layer 0: Y0 = spmm(adjZ, M*x)*AM ; H0 = relu(bn(Y0 @ W0^T + b0))
  spmm128_sorted<true><<<RB, 256, 0, stream>>>(rdZ, bins2Z, xm, AM, bufA, N);
  gemm_mfma128<false><<<GB64, 256, 0, stream>>>(bufA, Wb0, sc0, sh0, bufB,
                                                nullptr, nullptr, nullptr, N);

  // layer 1: Y1 = spmm(adj, H0) ; fused: H1 = relu(bn(Y1 @ W1^T + b1)) stays
  // on-chip, G2 = bf16(H1 @ W2^T) padded to 64 cols written directly.
  spmm128_sorted<false><<<RB, 256, 0, stream>>>(rdA, bins2A, bufB,
                                                (const float*)nullptr, bufA, N);
  gemm_mfma128<true><<<GB64, 256, 0, stream>>>(bufA, Wb1, sc1, sh1, nullptr,
                                               W2hi, W2lo, G2, N);

  // out = log_softmax(spmm(adj, G2) + b2)
  spmm_softmax64<<<RB, 256, 0, stream>>>(rdA, bins2A, G2, b2, out, N);
}